// Round 9
// baseline (190.666 us; speedup 1.0000x reference)
//
#include <hip/hip_runtime.h>
#include <hip/hip_bf16.h>
#include <math.h>

#define B_   16
#define CIN  64
#define COUT 64
#define H_   128
#define W_   128
#define KK   25
#define HW   (H_ * W_)
#define XT_PLANE ((size_t)B_ * HW * 32)   // shorts per 32-channel plane (16 MiB)
#define WTS ((size_t)COUT * H_ * 32)      // t2 w-tile panel stride in shorts

typedef short  bf16x8 __attribute__((ext_vector_type(8)));
typedef short  s16x4  __attribute__((ext_vector_type(4)));
typedef float  f32x16 __attribute__((ext_vector_type(16)));
typedef float  f32x4  __attribute__((ext_vector_type(4)));
typedef float  f32x2  __attribute__((ext_vector_type(2)));

__device__ __forceinline__ short f2bs(float v) {
    __hip_bfloat16 h = __float2bfloat16(v);
    return *reinterpret_cast<short*>(&h);
}
__device__ __forceinline__ float bs2f(short s) {
    unsigned int u = ((unsigned int)(unsigned short)s) << 16;
    return __uint_as_float(u);
}
// async 16B global->LDS (HW: per-lane global src, wave-uniform LDS base + lane*16)
__device__ __forceinline__ void gload_lds16(const short* g, short* l) {
    __builtin_amdgcn_global_load_lds(
        (const __attribute__((address_space(1))) void*)g,
        (__attribute__((address_space(3))) void*)l, 16, 0, 0);
}

// ---------------- Kernel 0: fused weight-prep + x-prep ----------------------
// z == B_ slice (x==0, y<COUT): wprep for oc = blockIdx.y — coalesced load of
//   w[o][*][*], 25 per-tap L2 norms over cin, scatter bf16 fragments:
//   wnb2[kk][ks][tile][lane][j] = wn[oc=tile*32+(lane&31)][cin=ks*16+(lane>>5)*8+j]
// z < B_: xprep — x -> channels-last bf16 planes xt[half][b*HW+p][32ch]
//   + per-pixel ssq xsqg[b*HW+p]. f32x4 vectorized x loads; ssq folded into
//   the LDS transpose pass.
__global__ __launch_bounds__(256) void k_prep(const float* __restrict__ x,
                                              const float* __restrict__ w,
                                              short* __restrict__ xt,
                                              float* __restrict__ xsqg,
                                              short* __restrict__ wnb2) {
    const int tid = threadIdx.x;

    if (blockIdx.z == B_) {               // ---- weight-prep slice
        if (blockIdx.x != 0 || blockIdx.y >= COUT) return;
        __shared__ float wl[CIN * KK];    // [i][kk] for this o
        __shared__ float inv[KK];
        const int o = blockIdx.y;

        for (int idx = tid; idx < CIN * KK; idx += 256)
            wl[idx] = w[(size_t)o * (CIN * KK) + idx];
        __syncthreads();
        if (tid < KK) {
            float s = 0.f;
            #pragma unroll 8
            for (int i = 0; i < CIN; ++i) { float v = wl[i * KK + tid]; s += v * v; }
            inv[tid] = 1.f / fmaxf(sqrtf(s), 1e-12f);
        }
        __syncthreads();
        const int tt = o >> 5, n = o & 31;
        for (int idx = tid; idx < CIN * KK; idx += 256) {   // ci fastest
            int ci = idx & 63, kk = idx >> 6;
            int ks = ci >> 4, q = (ci >> 3) & 1, j = ci & 7;
            int l = q * 32 + n;
            wnb2[((size_t)((kk * 4 + ks) * 2 + tt) * 64 + l) * 8 + j] =
                f2bs(fabsf(wl[ci * KK + kk]) * inv[kk]);
        }
        return;
    }

    // ---- x-prep slice
    __shared__ float tile[64][65];       // +1 pad: conflict-free both phases
    __shared__ float ps[8][64];
    const int b = blockIdx.z, h = blockIdx.y, w0 = blockIdx.x * 64;

    const float* xb = x + (size_t)b * CIN * HW + h * W_ + w0;
    {
        int c4 = tid & 15, g = tid >> 4;     // w-chunk 4*c4, ci-group 4*g
        #pragma unroll
        for (int k = 0; k < 4; ++k) {
            int ci = g * 4 + k;
            *(f32x4*)&tile[ci][c4 * 4] =
                *(const f32x4*)&xb[(size_t)ci * HW + c4 * 4];   // 256B/16-lane run
        }
    }
    __syncthreads();

    const size_t pixbase = (size_t)b * HW + h * W_ + w0;
    {
        int c8 = tid & 7;                    // 8-ci chunk: global ci = c8*8+j
        int half = c8 >> 2, sl = c8 & 3;     // plane, slot within plane
        short* dp = xt + (size_t)half * XT_PLANE;
        #pragma unroll
        for (int rep = 0; rep < 2; ++rep) {
            int p = (tid >> 3) + rep * 32;
            bf16x8 v; float sq = 0.f;
            #pragma unroll
            for (int j = 0; j < 8; ++j) {
                float f = tile[c8 * 8 + j][p];   // 2-way banks (free)
                sq += f * f;
                v[j] = f2bs(f);
            }
            ps[c8][p] = sq;                      // unique (c8,p) per rep
            *(bf16x8*)&dp[(pixbase + p) * 32 + sl * 8] = v;   // contiguous 1KB/wave
        }
    }
    __syncthreads();
    if (tid < 64) {
        float a = 0.f;
        #pragma unroll
        for (int c8 = 0; c8 < 8; ++c8) a += ps[c8][tid];
        xsqg[pixbase + tid] = a;
    }
}

// ---------------- Kernel 1: MFMA implicit-GEMM conv + cosine normalize -------
// Block: 256 thr = 4 waves; tile 8h x 32w x 64oc. NEW: cin streamed in FOUR
// 16-channel QUARTERS with a double-buffered LDS pipeline: quarter q+1 staged
// via async global_load_lds (width 16) BEFORE quarter q's 100-MFMA tap loop,
// one barrier per quarter. Staging has no VGPR round-trip / no ds_write; LDS
// layout is LINEAR [NS][16] (wave A-read = contiguous 1024B, conflict-free,
// and exactly the lane-order global_load_lds writes). K-loop math identical
// to R5/R8 (qtr == global 16-cin chunk ks).
#define NR 12            // window rows (8 + 4 halo)
#define NC 36            // window cols (32 + 4 halo)
#define NS (NR * NC)     // 432
#define NCH (NS * 2)     // 16B chunks per quarter buffer: 864
#define QBUF 8192        // shorts per staging buffer (1024 chunks incl. pad)
#define TP 264           // trans row stride in shorts

__global__ __launch_bounds__(256, 4) void k_conv(const short* __restrict__ xt,
                                                 const float* __restrict__ xsqg,
                                                 const short* __restrict__ wnb2,
                                                 short* __restrict__ t2) {
    // LDS pool 37248 B -> 4 blocks/CU:
    //   [0,32768)      xin2: 2 x QBUF shorts (double-buffered quarter)
    //   [32768,34496)  s2win[NS] float
    //   [34496,36224)  soff [NS] int
    //   [36224,37248)  xsq  [256] float
    //   epilogue: trans[64][TP] = 33792 B reuses [0,33792) (xin2+s2win dead)
    __shared__ __align__(16) short pool[18624];
    short* xin   = pool;
    float* s2win = (float*)&pool[16384];
    int*   soff  = (int*)&pool[17248];
    float* xsq   = (float*)&pool[18112];

    const int tid  = threadIdx.x;
    const int lane = tid & 63;
    const int wv   = tid >> 6;
    const int n    = lane & 31;
    const int q    = lane >> 5;
    const int b    = blockIdx.z;
    const int h0   = blockIdx.y * 8;
    const int wt   = blockIdx.x;          // w-tile index (w0 = wt*32)
    const int w0   = wt * 32;

    const size_t pixbase = (size_t)b * HW;

    // ---- reflect map + gather of precomputed per-pixel ssq
    for (int s = tid; s < NS; s += 256) {
        int r = s / NC, c = s - r * NC;
        int hh = h0 - 2 + r; hh = hh < 0 ? -hh : (hh > H_ - 1 ? 2 * (H_ - 1) - hh : hh);
        int ww = w0 - 2 + c; ww = ww < 0 ? -ww : (ww > W_ - 1 ? 2 * (W_ - 1) - ww : ww);
        int off = hh * W_ + ww;
        soff[s] = off;
        s2win[s] = xsqg[pixbase + off];
    }
    __syncthreads();

    // ---- xsq per output pixel (8 x 32): 5x5 window sum of s2win
    {
        int hr = tid >> 5, cl = tid & 31;
        float a = 0.f;
        #pragma unroll
        for (int kh = 0; kh < 5; ++kh)
            #pragma unroll
            for (int kw = 0; kw < 5; ++kw)
                a += s2win[(hr + kh) * NC + cl + kw];
        xsq[tid] = a;
    }

    // ---- async stage of one 16-cin quarter into buffer bs
    auto stage = [&](int qtr, int bs) {
        const short* xph = xt + (size_t)(qtr >> 1) * XT_PLANE + pixbase * 32
                              + (qtr & 1) * 16;
        #pragma unroll
        for (int k = 0; k < 4; ++k) {
            int i = k * 256 + tid;
            int ic = i < NCH ? i : NCH - 1;          // clamp tail into pad slots
            int s = ic >> 1, c = ic & 1;
            const short* src = xph + (size_t)soff[s] * 32 + c * 8;
            short* dst = xin + bs * QBUF + (k * 256 + wv * 64) * 8;  // wave-uniform
            gload_lds16(src, dst);
        }
    };

    const short* wb = wnb2 + (size_t)lane * 8;   // per-lane fragment base

    f32x16 acc00, acc01, acc10, acc11;
    #pragma unroll
    for (int i = 0; i < 16; ++i) { acc00[i] = 0.f; acc01[i] = 0.f; acc10[i] = 0.f; acc11[i] = 0.f; }

    stage(0, 0);
    __syncthreads();                 // drains vmcnt: buf0 ready

    for (int qtr = 0; qtr < 4; ++qtr) {
        const int bs = qtr & 1;
        if (qtr < 3) stage(qtr + 1, bs ^ 1);      // async, lands in other buffer

        // ---- tap loop: 25 taps x 16 cin, reads buf bs, B direct from global
        #pragma unroll 5
        for (int kk = 0; kk < KK; ++kk) {
            const int kh = kk / 5, kw = kk % 5;
            const int sp0 = (2 * wv + kh) * NC + n + kw;
            const int ka = bs * QBUF + q * 8;
            bf16x8 a0 = *(const bf16x8*)&xin[ka + sp0 * 16];
            bf16x8 a1 = *(const bf16x8*)&xin[ka + (sp0 + NC) * 16];
            bf16x8 b0 = *(const bf16x8*)&wb[(size_t)((kk * 4 + qtr) * 2 + 0) * 512];
            bf16x8 b1 = *(const bf16x8*)&wb[(size_t)((kk * 4 + qtr) * 2 + 1) * 512];
            acc00 = __builtin_amdgcn_mfma_f32_32x32x16_bf16(a0, b0, acc00, 0, 0, 0);
            acc01 = __builtin_amdgcn_mfma_f32_32x32x16_bf16(a0, b1, acc01, 0, 0, 0);
            acc10 = __builtin_amdgcn_mfma_f32_32x32x16_bf16(a1, b0, acc10, 0, 0, 0);
            acc11 = __builtin_amdgcn_mfma_f32_32x32x16_bf16(a1, b1, acc11, 0, 0, 0);
        }
        __syncthreads();   // drains vmcnt (next buf ready) + fences buf reuse
    }

    // ---- epilogue: y = acc * rsqrt(xsq); transpose via LDS; full-line store
    short* trans = pool;
    const int hrA = 2 * wv, hrB = 2 * wv + 1;
    #pragma unroll
    for (int g4 = 0; g4 < 4; ++g4) {
        int wc0 = 8 * g4 + 4 * q;
        s16x4 v00, v01, v10, v11;
        #pragma unroll
        for (int j = 0; j < 4; ++j) {
            float ia = rsqrtf(xsq[hrA * 32 + wc0 + j] + 1e-8f);
            float ib = rsqrtf(xsq[hrB * 32 + wc0 + j] + 1e-8f);
            v00[j] = f2bs(acc00[4 * g4 + j] * ia);
            v01[j] = f2bs(acc01[4 * g4 + j] * ia);
            v10[j] = f2bs(acc10[4 * g4 + j] * ib);
            v11[j] = f2bs(acc11[4 * g4 + j] * ib);
        }
        *(s16x4*)&trans[n * TP        + hrA * 32 + wc0] = v00;
        *(s16x4*)&trans[(32 + n) * TP + hrA * 32 + wc0] = v01;
        *(s16x4*)&trans[n * TP        + hrB * 32 + wc0] = v10;
        *(s16x4*)&trans[(32 + n) * TP + hrB * 32 + wc0] = v11;
    }
    __syncthreads();

    short* tbase = t2 + ((size_t)(b * 4 + wt) * COUT) * (H_ * 32);
    #pragma unroll
    for (int u = tid; u < 512; u += 256) { // (oc, hr): 64B contiguous runs
        int oc = u >> 3, hr = u & 7;
        const short* src = &trans[oc * TP + hr * 32];
        short* dst = tbase + ((size_t)oc * H_ + h0 + hr) * 32;
        float4 a0 = *(const float4*)(src);
        float4 a1 = *(const float4*)(src + 8);
        float4 a2 = *(const float4*)(src + 16);
        float4 a3 = *(const float4*)(src + 24);
        *(float4*)(dst)      = a0;
        *(float4*)(dst + 8)  = a1;
        *(float4*)(dst + 16) = a2;
        *(float4*)(dst + 24) = a3;
    }
}

// ---------------- Kernel 2: depthwise 5x5 DoG, zero pad, fp32 out ------------
// 64-row tiles; reads the w-tile-major t2 layout (4 x 64B gathers per row).
__global__ __launch_bounds__(256) void k_dog(const short* __restrict__ t2,
                                             float* __restrict__ out) {
    __shared__ float tile[68 * 132];
    __shared__ float sm_s[25];
    const int bo  = blockIdx.y;
    const int h0  = blockIdx.x * 64;
    const int tid = threadIdx.x;

    if (tid < 25) {
        const float se2 = 2.f * 1.2f * 1.2f;
        const float si2 = 2.f * 1.4f * 1.4f;
        const float twopi = 6.28318530717958647692f;
        const float ae = 1.f / (twopi * 1.2f * 1.2f);
        const float ai = 1.f / (twopi * 1.4f * 1.4f);
        const float c0 = ae - ai;
        int dx = tid / 5 - 2, dy = tid % 5 - 2;
        float r2 = (float)(dx * dx + dy * dy);
        sm_s[tid] = (ae * expf(-r2 / se2) - ai * expf(-r2 / si2)) / c0;
    }

    // interior: cols 2..129 of tile <- w 0..127
    const int bb = bo >> 6, oc = bo & 63;
    const short* base = t2 + ((size_t)(bb * 4) * COUT + oc) * (H_ * 32);
    for (int idx = tid; idx < 68 * 16; idx += 256) {
        int rr = idx >> 4, g = idx & 15;
        int hh = h0 - 2 + rr;
        float v[8];
        if (hh >= 0 && hh < H_) {
            int wtile = g >> 2, c = g & 3;
            bf16x8 a = *(const bf16x8*)&base[(size_t)wtile * WTS + (size_t)hh * 32 + c * 8];
            #pragma unroll
            for (int j = 0; j < 8; ++j) v[j] = bs2f(a[j]);
        } else {
            #pragma unroll
            for (int j = 0; j < 8; ++j) v[j] = 0.f;
        }
        float* dst = &tile[rr * 132 + 2 + g * 8];
        *(f32x2*)(dst)     = (f32x2){v[0], v[1]};
        *(f32x4*)(dst + 2) = (f32x4){v[2], v[3], v[4], v[5]};
        *(f32x2*)(dst + 6) = (f32x2){v[6], v[7]};
    }
    // zero-pad edge columns (w = -2,-1,128,129 -> tile cols 0,1,130,131)
    for (int idx = tid; idx < 68 * 4; idx += 256) {
        int rr = idx >> 2, c = idx & 3;
        tile[rr * 132 + (c < 2 ? c : 128 + c)] = 0.f;
    }
    __syncthreads();

    float smr[25];
    #pragma unroll
    for (int kk = 0; kk < 25; ++kk) smr[kk] = sm_s[kk];

    const int cq = tid & 31;
    const int r0 = tid >> 5;
    #pragma unroll
    for (int rr = 0; rr < 8; ++rr) {
        int r = r0 + 8 * rr;
        float s0 = 0.f, s1 = 0.f, s2 = 0.f, s3 = 0.f;
        #pragma unroll
        for (int kh = 0; kh < 5; ++kh) {
            const float* row = &tile[(r + kh) * 132 + cq * 4];
            f32x4 v0 = *(const f32x4*)(row);
            f32x4 v1 = *(const f32x4*)(row + 4);
            float vv[8] = { v0[0], v0[1], v0[2], v0[3], v1[0], v1[1], v1[2], v1[3] };
            #pragma unroll
            for (int kw = 0; kw < 5; ++kw) {
                float cf = smr[kh * 5 + kw];
                s0 += cf * vv[kw];
                s1 += cf * vv[kw + 1];
                s2 += cf * vv[kw + 2];
                s3 += cf * vv[kw + 3];
            }
        }
        float4 o4 = make_float4(s0, s1, s2, s3);
        *(float4*)&out[((size_t)bo * H_ + h0 + r) * W_ + cq * 4] = o4;
    }
}

// -----------------------------------------------------------------------------
extern "C" void kernel_launch(void* const* d_in, const int* in_sizes, int n_in,
                              void* d_out, int out_size, void* d_ws, size_t ws_size,
                              hipStream_t stream) {
    const float* x = (const float*)d_in[0];
    const float* w = (const float*)d_in[1];

    short* t2 = (short*)d_ws;    // 32 MiB w-tile-major intermediate

    // d_out (64 MiB) scratch layout, all fully overwritten by k_dog at the end:
    //   [0, 32 MiB)         xt: two channels-last bf16 planes
    //   [32 MiB, +1 MiB)    xsqg: per-pixel sum of x^2 over cin
    //   [64 MiB - 200 KiB)  wnb2: fragment-ordered normalized bf16 weights
    short* xt    = (short*)d_out;
    float* xsqg  = (float*)((char*)d_out + 33554432);
    short* wnb2  = (short*)((char*)d_out + (size_t)67108864 - 204800);

    dim3 gx(W_ / 64, H_, B_ + 1);    // z==B_ slice runs weight-prep
    k_prep<<<gx, 256, 0, stream>>>(x, w, xt, xsqg, wnb2);

    dim3 g2(W_ / 32, H_ / 8, B_);    // 4 x 16 x 16 = 1024 blocks
    k_conv<<<g2, 256, 0, stream>>>(xt, xsqg, wnb2, t2);

    dim3 g3(H_ / 64, B_ * COUT);     // 2 x 1024 blocks
    k_dog<<<g3, 256, 0, stream>>>(t2, (float*)d_out);
}